// Round 8
// baseline (276.076 us; speedup 1.0000x reference)
//
#include <hip/hip_runtime.h>
#include <hip/hip_bf16.h>

#define N_NODES 131072
#define B_SEG   2048
#define F_DIM   200
#define K_DIM   608      // 400 (q_star) + 200 (h) + 8 zero pad = 19*32
#define NEG_INF (-3.4e38f)
#define NMAX    512      // max rows per segment supported (actual max ~110)

typedef __attribute__((ext_vector_type(8))) short bf16x8;
typedef __attribute__((ext_vector_type(4))) float f32x4;

__device__ __forceinline__ float b2f(unsigned short u) {
  union { unsigned int i; float f; } v; v.i = ((unsigned int)u) << 16; return v.f;
}
__device__ __forceinline__ unsigned short f2bu(float f) {
  __hip_bfloat16 h = __float2bfloat16(f);
  return *reinterpret_cast<unsigned short*>(&h);
}
__device__ __forceinline__ float sigmoidf_(float x) { return 1.f / (1.f + __expf(-x)); }
__device__ __forceinline__ float tanhf_(float x) {
  float e = __expf(2.f * x);
  return 1.f - 2.f / (1.f + e);
}
// first index i with batch[i] >= target (batch sorted ascending)
__device__ __forceinline__ int lower_bound_batch(const int* __restrict__ batch, int target) {
  int lo = 0, hi = N_NODES;
  while (lo < hi) {
    int mid = (lo + hi) >> 1;
    if (batch[mid] < target) lo = mid + 1; else hi = mid;
  }
  return lo;
}

// ---------------------------------------------------------------------
// init: W pack + bias sum + seg bounds + x->bf16 conversion (prefetched,
// fire-and-forget stores) + a_sit (f32 accumulate, cosc in LDS) + qs0 pack.
// grid 2048 x 256 (block b owns segment b)
// ---------------------------------------------------------------------
__global__ __launch_bounds__(256) void init_kernel(
    const float* __restrict__ xf, const int* __restrict__ batch,
    const float* __restrict__ cosc, const float* __restrict__ qs0,
    const float* __restrict__ Wih, const float* __restrict__ Whh,
    const float* __restrict__ bih, const float* __restrict__ bhh,
    unsigned short* __restrict__ xb, unsigned short* __restrict__ A,
    unsigned short* __restrict__ Wc, float* __restrict__ bsum,
    int* __restrict__ seg_off) {
  __shared__ float rpart[5][F_DIM];
  __shared__ float cw[NMAX];
  __shared__ int sb[2];
  int b = blockIdx.x, tid = threadIdx.x;
  if (tid < 2) sb[tid] = lower_bound_batch(batch, b + tid);
  // 2048*256 = 524288 threads >= 832*608 = 505856 (single element each)
  int idx = b * 256 + tid;
  if (idx < 832 * K_DIM) {
    int row = idx / K_DIM, k = idx - row * K_DIM;
    float v = 0.f;
    if (row < 800) {
      if (k < 400)      v = Wih[row * 400 + k];
      else if (k < 600) v = Whh[row * 200 + (k - 400)];
    }
    Wc[idx] = f2bu(v);
  }
  if (idx < 800) bsum[idx] = bih[idx] + bhh[idx];
  __syncthreads();
  int start = sb[0], end = sb[1];
  int n = end - start; if (n > NMAX) n = NMAX;
  if (tid == 0) {
    seg_off[b] = start;
    if (b == 0) seg_off[B_SEG] = N_NODES;
  }
  for (int r = tid; r < n; r += 256) cw[r] = cosc[start + r];
  __syncthreads();                       // cw ready
  unsigned short* Arow = A + (size_t)b * K_DIM;
  int rgrp = tid / 50, col4 = tid - rgrp * 50;   // rgrp 0..4 active, col4 0..49
  float a0 = 0.f, a1 = 0.f, a2 = 0.f, a3 = 0.f;
  if (rgrp < 5) {
    const float* xp = xf + (size_t)start * F_DIM + 4 * col4;
    unsigned short* xw = xb + (size_t)start * F_DIM + 4 * col4;
    int r = rgrp;
    float4 v = {0.f, 0.f, 0.f, 0.f};
    if (r < n) v = *(const float4*)(xp + (size_t)r * F_DIM);
    for (; r < n; r += 5) {
      float4 vc = v;
      int rn = r + 5;
      if (rn < n) v = *(const float4*)(xp + (size_t)rn * F_DIM);  // prefetch
      ushort4 o;                          // bf16 conversion, fire-and-forget store
      o.x = f2bu(vc.x); o.y = f2bu(vc.y); o.z = f2bu(vc.z); o.w = f2bu(vc.w);
      *(ushort4*)(xw + (size_t)r * F_DIM) = o;
      float cv = cw[r];
      a0 += cv * vc.x; a1 += cv * vc.y; a2 += cv * vc.z; a3 += cv * vc.w;
    }
    rpart[rgrp][4 * col4]     = a0;
    rpart[rgrp][4 * col4 + 1] = a1;
    rpart[rgrp][4 * col4 + 2] = a2;
    rpart[rgrp][4 * col4 + 3] = a3;
  }
  if (tid < 100) {                       // qs0 row: 400 f32 -> 400 bf16
    float4 v = *(const float4*)(qs0 + (size_t)b * 400 + 4 * tid);
    ushort4 o; o.x = f2bu(v.x); o.y = f2bu(v.y); o.z = f2bu(v.z); o.w = f2bu(v.w);
    *(ushort4*)(Arow + 4 * tid) = o;
  }
  if (tid < 8) Arow[600 + tid] = 0;
  __syncthreads();
  if (tid < F_DIM) {
    float acc = rpart[0][tid] + rpart[1][tid] + rpart[2][tid] + rpart[3][tid]
              + rpart[4][tid];
    Arow[400 + tid] = f2bu(acc);
  }
}

// ---- gates GEMM (champion verbatim), barrier-free, BM=32/BN=64: 832 blocks ----
__global__ __launch_bounds__(256) void gemm_gates(
    const unsigned short* __restrict__ A, const unsigned short* __restrict__ W,
    float* __restrict__ gates) {
  int tid = threadIdx.x;
  int bm = blockIdx.x * 32, bn = blockIdx.y * 64;
  int wave = tid >> 6, lane = tid & 63;
  int quad = lane >> 4, col = lane & 15;
  int strip = wave >> 1;                  // 0..1 : 16-row strip
  int tp = (wave & 1) * 2;                // 0 or 2 : N-tile pair
  f32x4 acc[2];
  acc[0] = (f32x4){0.f, 0.f, 0.f, 0.f};
  acc[1] = (f32x4){0.f, 0.f, 0.f, 0.f};
  const unsigned short* Ap = A + (size_t)(bm + strip * 16 + col) * K_DIM + quad * 8;
  const unsigned short* Wp = W + (size_t)(bn + col) * K_DIM + quad * 8;
#pragma unroll
  for (int k0 = 0; k0 < K_DIM; k0 += 32) {
    bf16x8 af = *(const bf16x8*)(Ap + k0);
#pragma unroll
    for (int t = 0; t < 2; t++) {
      bf16x8 bfr = *(const bf16x8*)(Wp + (size_t)(tp + t) * 16 * K_DIM + k0);
      acc[t] = __builtin_amdgcn_mfma_f32_16x16x32_bf16(af, bfr, acc[t], 0, 0, 0);
    }
  }
#pragma unroll
  for (int t = 0; t < 2; t++) {
    int gn = bn + (tp + t) * 16 + col;
    if (gn < 800) {
#pragma unroll
      for (int r = 0; r < 4; r++) {
        int gm = bm + strip * 16 + quad * 4 + r;
        gates[(size_t)gm * 800 + gn] = acc[t][r];
      }
    }
  }
}

// ---- fused LSTM cell + online-softmax attention ----
// Row-PAIRED inner loop: 2 rows/iter/half-wave, shared lazy rescale.
__global__ __launch_bounds__(256) void attn_fused(
    const unsigned short* __restrict__ xb, const int* __restrict__ seg_off,
    const float* __restrict__ gates, const float* __restrict__ bsum,
    float* __restrict__ cvec, unsigned short* __restrict__ A,
    float* __restrict__ out, int step) {
  __shared__ float q_s[F_DIM];
  __shared__ float rpart[8][F_DIM];
  __shared__ float redm[8], redl[8];
  int b = blockIdx.x, tid = threadIdx.x;
  int start = seg_off[b], end = seg_off[b + 1];
  int n = end - start;
  unsigned short* Arow = A + (size_t)b * K_DIM;
  // LSTM cell for this segment's 200 features
  if (tid < F_DIM) {
    int f = tid;
    const float* g = gates + (size_t)b * 800;
    float gi = g[f]       + bsum[f];
    float gf = g[200 + f] + bsum[200 + f];
    float gg = g[400 + f] + bsum[400 + f];
    float go = g[600 + f] + bsum[600 + f];
    float cp = (step > 0) ? cvec[(size_t)b * F_DIM + f] : 0.f;
    float cn = sigmoidf_(gf) * cp + sigmoidf_(gi) * tanhf_(gg);
    float hn = sigmoidf_(go) * tanhf_(cn);
    if (step < 2) cvec[(size_t)b * F_DIM + f] = cn;
    q_s[f] = hn;
    if (step < 2) {
      unsigned short hb = f2bu(hn);
      Arow[f] = hb;                       // q part of next q_star
      Arow[400 + f] = hb;                 // hidden for next cell
    }
  }
  __syncthreads();
  int wave = tid >> 6, lane = tid & 63;
  int half = lane >> 5, hl = lane & 31;   // 32-lane half-wave
  int hw = wave * 2 + half;               // 0..7 : row owner
  bool act = (hl < 25);                   // 25 lanes x 8 elems = 200 features
  float q0=0,q1=0,q2=0,q3=0,q4=0,q5=0,q6=0,q7=0;
  if (act) {
    q0 = q_s[8*hl];   q1 = q_s[8*hl+1]; q2 = q_s[8*hl+2]; q3 = q_s[8*hl+3];
    q4 = q_s[8*hl+4]; q5 = q_s[8*hl+5]; q6 = q_s[8*hl+6]; q7 = q_s[8*hl+7];
  }
  const unsigned short* xp = xb + (size_t)start * F_DIM + 8 * hl;
  // online softmax: paired rows (r, r+8), step 16, 1-deep pair prefetch
  float m = NEG_INF, l = 0.f;
  float a0=0,a1=0,a2=0,a3=0,a4=0,a5=0,a6=0,a7=0;
  int r = hw;
  uint4 v1 = {0u,0u,0u,0u}, v2 = {0u,0u,0u,0u};
  if (act && r < n)     v1 = *(const uint4*)(xp + (size_t)r * F_DIM);
  if (act && r + 8 < n) v2 = *(const uint4*)(xp + (size_t)(r + 8) * F_DIM);
  for (; r < n; r += 16) {
    uint4 c1 = v1, c2 = v2;
    bool has2 = (r + 8) < n;
    int rn = r + 16;
    if (act && rn < n)     v1 = *(const uint4*)(xp + (size_t)rn * F_DIM);
    if (act && rn + 8 < n) v2 = *(const uint4*)(xp + (size_t)(rn + 8) * F_DIM);
    float x10 = b2f((unsigned short)(c1.x & 0xffff)), x11 = b2f((unsigned short)(c1.x >> 16));
    float x12 = b2f((unsigned short)(c1.y & 0xffff)), x13 = b2f((unsigned short)(c1.y >> 16));
    float x14 = b2f((unsigned short)(c1.z & 0xffff)), x15 = b2f((unsigned short)(c1.z >> 16));
    float x16 = b2f((unsigned short)(c1.w & 0xffff)), x17 = b2f((unsigned short)(c1.w >> 16));
    float x20 = b2f((unsigned short)(c2.x & 0xffff)), x21 = b2f((unsigned short)(c2.x >> 16));
    float x22 = b2f((unsigned short)(c2.y & 0xffff)), x23 = b2f((unsigned short)(c2.y >> 16));
    float x24 = b2f((unsigned short)(c2.z & 0xffff)), x25 = b2f((unsigned short)(c2.z >> 16));
    float x26 = b2f((unsigned short)(c2.w & 0xffff)), x27 = b2f((unsigned short)(c2.w >> 16));
    float p1 = q0*x10 + q1*x11 + q2*x12 + q3*x13 + q4*x14 + q5*x15 + q6*x16 + q7*x17;
    float p2 = q0*x20 + q1*x21 + q2*x22 + q3*x23 + q4*x24 + q5*x25 + q6*x26 + q7*x27;
    // two independent butterflies dual-issue (amortize shfl latency 2x)
#pragma unroll
    for (int off = 16; off; off >>= 1) {
      p1 += __shfl_xor(p1, off, 32);
      p2 += __shfl_xor(p2, off, 32);
    }
    float e1 = p1;
    float e2 = has2 ? p2 : NEG_INF;
    float mn = fmaxf(m, fmaxf(e1, e2));
    float w1 = __expf(e1 - mn);
    float w2 = __expf(e2 - mn);           // invalid row2 -> exp(-inf)=0
    if (mn > m) {                         // lazy rescale (skipped fac==1 exactly)
      float fac = __expf(m - mn);         // first iter: exp(-inf)=0 zeroes l,a
      l *= fac;
      a0 *= fac; a1 *= fac; a2 *= fac; a3 *= fac;
      a4 *= fac; a5 *= fac; a6 *= fac; a7 *= fac;
      m = mn;
    }
    l += w1 + w2;
    a0 += w1*x10 + w2*x20; a1 += w1*x11 + w2*x21;
    a2 += w1*x12 + w2*x22; a3 += w1*x13 + w2*x23;
    a4 += w1*x14 + w2*x24; a5 += w1*x15 + w2*x25;
    a6 += w1*x16 + w2*x26; a7 += w1*x17 + w2*x27;
  }
  // cross-half-wave combine: 8 (m,l,a) triples
  if (hl == 0) redm[hw] = m;
  __syncthreads();
  float M = fmaxf(fmaxf(fmaxf(redm[0], redm[1]), fmaxf(redm[2], redm[3])),
                  fmaxf(fmaxf(redm[4], redm[5]), fmaxf(redm[6], redm[7])));
  float facw = (m > NEG_INF) ? __expf(m - M) : 0.f;
  if (hl == 0) redl[hw] = l * facw;
  if (act) {
    float* rp = &rpart[hw][8 * hl];
    rp[0] = a0*facw; rp[1] = a1*facw; rp[2] = a2*facw; rp[3] = a3*facw;
    rp[4] = a4*facw; rp[5] = a5*facw; rp[6] = a6*facw; rp[7] = a7*facw;
  }
  __syncthreads();
  float L = redl[0]+redl[1]+redl[2]+redl[3]+redl[4]+redl[5]+redl[6]+redl[7];
  float inv = (L > 0.f) ? 1.f / L : 0.f;
  if (tid < F_DIM) {
    float rv = (rpart[0][tid]+rpart[1][tid]+rpart[2][tid]+rpart[3][tid]
              + rpart[4][tid]+rpart[5][tid]+rpart[6][tid]+rpart[7][tid]) * inv;
    if (step < 2) {
      Arow[200 + tid] = f2bu(rv);
    } else {
      out[(size_t)b * 400 + tid]       = q_s[tid];
      out[(size_t)b * 400 + 200 + tid] = rv;
    }
  }
}

extern "C" void kernel_launch(void* const* d_in, const int* in_sizes, int n_in,
                              void* d_out, int out_size, void* d_ws, size_t ws_size,
                              hipStream_t stream) {
  const float* x    = (const float*)d_in[0];
  const int*   batch= (const int*)d_in[1];
  const float* cosc = (const float*)d_in[2];
  const float* qs0  = (const float*)d_in[3];
  const float* Wih  = (const float*)d_in[4];
  const float* Whh  = (const float*)d_in[5];
  const float* bih  = (const float*)d_in[6];
  const float* bhh  = (const float*)d_in[7];
  char* ws = (char*)d_ws;
  // ws layout (bytes, all 16B aligned), total ~64.2 MB:
  unsigned short* xb   = (unsigned short*)(ws);               // 131072*200*2 = 52,428,800
  unsigned short* A    = (unsigned short*)(ws + 52428800);    // 2048*608*2   =  2,490,368
  unsigned short* Wc   = (unsigned short*)(ws + 54919168);    // 832*608*2    =  1,011,712
  float*          gates= (float*)(ws + 55930880);             // 2048*800*4   =  6,553,600
  float*          cvec = (float*)(ws + 62484480);             // 2048*200*4   =  1,638,400
  float*          bsum = (float*)(ws + 64122880);             // 800*4        =      3,200
  int*            soff = (int*)(ws + 64126080);               // 2052*4       =      8,208
  float*          outp = (float*)d_out;

  init_kernel<<<B_SEG, 256, 0, stream>>>(x, batch, cosc, qs0, Wih, Whh, bih, bhh,
                                         xb, A, Wc, bsum, soff);
  for (int s = 0; s < 3; s++) {
    gemm_gates<<<dim3(64, 13), 256, 0, stream>>>(A, Wc, gates);
    attn_fused<<<B_SEG, 256, 0, stream>>>(xb, soff, gates, bsum, cvec, A, outp, s);
  }
}